// Round 2
// baseline (2112.308 us; speedup 1.0000x reference)
//
#include <hip/hip_runtime.h>
#include <cstdint>
#include <cstddef>

#define B_ 4
#define S_ 2048
#define E_ 2048
#define H_ 16
#define DH_ 128
#define F_ 8192
#define NTOK (B_*S_)
#define QKVN (3*E_)

typedef __attribute__((ext_vector_type(4))) float f32x4;
typedef __attribute__((ext_vector_type(8))) __bf16 bf16x8;
typedef __attribute__((ext_vector_type(8))) short s16x8;
typedef __attribute__((ext_vector_type(4))) short s16x4;

using gas_ptr = const __attribute__((address_space(1))) void*;
using las_ptr = __attribute__((address_space(3))) void*;

__device__ __forceinline__ short f2bf(float f) {
  union { float f; uint32_t u; } v{f};
  uint32_t r = v.u + 0x7FFFu + ((v.u >> 16) & 1u);   // round-to-nearest-even
  return (short)(r >> 16);
}
__device__ __forceinline__ float bf2f(short s) {
  union { uint32_t u; float f; } v;
  v.u = ((uint32_t)(uint16_t)s) << 16;
  return v.f;
}

// ---------------- RMSNorm + RoPE -> bf16 ----------------
__global__ __launch_bounds__(256) void k_rms_rope(const float* __restrict__ x,
                                                  const float* __restrict__ gamma,
                                                  const int* __restrict__ pos,
                                                  short* __restrict__ y) {
  const int row = blockIdx.x;
  const int s = row & (S_ - 1);
  const int t = threadIdx.x;
  const int head = t >> 4;
  const int j0 = (t & 15) << 2;
  const float* xr = x + (size_t)row * E_;
  const int c1 = head * DH_ + j0;
  const int c2 = c1 + 64;
  f32x4 x1 = *(const f32x4*)(xr + c1);
  f32x4 x2 = *(const f32x4*)(xr + c2);
  float ss = x1[0]*x1[0]+x1[1]*x1[1]+x1[2]*x1[2]+x1[3]*x1[3]
           + x2[0]*x2[0]+x2[1]*x2[1]+x2[2]*x2[2]+x2[3]*x2[3];
  #pragma unroll
  for (int off = 32; off >= 1; off >>= 1) ss += __shfl_xor(ss, off, 64);
  __shared__ float red[4];
  __shared__ float rsh;
  if ((t & 63) == 0) red[t >> 6] = ss;
  __syncthreads();
  if (t == 0) rsh = rsqrtf((red[0]+red[1]+red[2]+red[3]) * (1.0f / E_) + 1e-5f);
  __syncthreads();
  const float r = rsh;
  f32x4 g1 = *(const f32x4*)(gamma + c1);
  f32x4 g2 = *(const f32x4*)(gamma + c2);
  const float p = (float)pos[s];
  s16x4 o1, o2;
  #pragma unroll
  for (int jj = 0; jj < 4; ++jj) {
    float fi = exp2f((float)(j0 + jj) * (-13.287712379549449f / 64.0f));
    float ang = p * fi;
    float sn, cs;
    sincosf(ang, &sn, &cs);
    float a = x1[jj] * r * g1[jj];
    float b = x2[jj] * r * g2[jj];
    o1[jj] = f2bf(a * cs - b * sn);
    o2[jj] = f2bf(b * cs + a * sn);
  }
  *(s16x4*)(y + (size_t)row * E_ + c1) = o1;
  *(s16x4*)(y + (size_t)row * E_ + c2) = o2;
}

// ---------------- RMSNorm (no rope), fp32 in -> bf16 ----------------
__global__ __launch_bounds__(256) void k_rms(const float* __restrict__ x,
                                             const float* __restrict__ gamma,
                                             short* __restrict__ y) {
  const int row = blockIdx.x;
  const int t = threadIdx.x;
  const int c = t << 3;
  const float* xr = x + (size_t)row * E_;
  f32x4 a = *(const f32x4*)(xr + c);
  f32x4 b = *(const f32x4*)(xr + c + 4);
  float ss = a[0]*a[0]+a[1]*a[1]+a[2]*a[2]+a[3]*a[3]
           + b[0]*b[0]+b[1]*b[1]+b[2]*b[2]+b[3]*b[3];
  #pragma unroll
  for (int off = 32; off >= 1; off >>= 1) ss += __shfl_xor(ss, off, 64);
  __shared__ float red[4];
  __shared__ float rsh;
  if ((t & 63) == 0) red[t >> 6] = ss;
  __syncthreads();
  if (t == 0) rsh = rsqrtf((red[0]+red[1]+red[2]+red[3]) * (1.0f / E_) + 1e-5f);
  __syncthreads();
  const float r = rsh;
  f32x4 ga = *(const f32x4*)(gamma + c);
  f32x4 gb = *(const f32x4*)(gamma + c + 4);
  s16x8 o;
  #pragma unroll
  for (int jj = 0; jj < 4; ++jj) {
    o[jj]   = f2bf(a[jj] * r * ga[jj]);
    o[4+jj] = f2bf(b[jj] * r * gb[jj]);
  }
  *(s16x8*)(y + (size_t)row * E_ + c) = o;
}

// ---------------- fp32 (R,C) -> bf16 (C,R) transpose ----------------
__global__ __launch_bounds__(256) void k_transpose_f32_bf16(const float* __restrict__ src,
                                                            short* __restrict__ dst,
                                                            int R, int C) {
  __shared__ float tile[32][33];
  const int c0 = blockIdx.x << 5, r0 = blockIdx.y << 5;
  const int tx = threadIdx.x & 31, ty = threadIdx.x >> 5;
  #pragma unroll
  for (int j = 0; j < 32; j += 8)
    tile[ty + j][tx] = src[(size_t)(r0 + ty + j) * C + c0 + tx];
  __syncthreads();
  #pragma unroll
  for (int j = 0; j < 32; j += 8)
    dst[(size_t)(c0 + ty + j) * R + r0 + tx] = f2bf(tile[tx][ty + j]);
}

// ---------------- V section of QKV -> per-(b,h) V^T (bf16) ----------------
__global__ __launch_bounds__(256) void k_transpose_v(const short* __restrict__ qkv,
                                                     short* __restrict__ vt) {
  __shared__ short tile[32][33];
  const int bh = blockIdx.z;
  const short* src = qkv + (size_t)(bh >> 4) * S_ * QKVN + 2 * E_ + (bh & 15) * DH_;
  short* dst = vt + (size_t)bh * DH_ * S_;
  const int s0 = blockIdx.x << 5, d0 = blockIdx.y << 5;
  const int tx = threadIdx.x & 31, ty = threadIdx.x >> 5;
  #pragma unroll
  for (int j = 0; j < 32; j += 8)
    tile[ty + j][tx] = src[(size_t)(s0 + ty + j) * QKVN + d0 + tx];
  __syncthreads();
  #pragma unroll
  for (int j = 0; j < 32; j += 8)
    dst[(size_t)(d0 + ty + j) * S_ + s0 + tx] = tile[tx][ty + j];
}

// ---------------- 256x256-tile 8-phase bf16 GEMM (counted-vmcnt schedule) ----------
// C[M,N] = A[M,K] * Bt[N,K]^T.  512 threads = 8 waves (2M x 4N); per-wave output
// 128x64 = acc[8][4] 16x16 fragments.  BK=64 split into two K-halves of 32.
// LDS rings: A = 5 slots, B = 4 slots, each slot [256 rows][32 cols] bf16 = 16 KiB
// -> 80 + 64 = 144 KiB, 1 block/CU, 8 waves.  Slot of K-half sidx = (2*tile+kh):
// A slot = sidx % 5, B slot = sidx & 3.
// Stage stream: one half-tile per phase, h = 4t+7+p in tile t's phase p
// (p0->B1(t+1), p1->A0(t+2), p2->B0(t+2), p3->A1(t+2)); 3 half-tiles in flight,
// s_waitcnt vmcnt(6) ONCE per K-tile, never 0 (T3+T4).
// RACE-FREE BY BARRIER ORDER (round-0 post-mortem): with ring sizes 5/4, each
// stage evicts the slot of sidx-ring_size, whose last ds_read completed >=2
// barriers before the stage ISSUES (>=1 barrier even if the compiler hoists the
// stage past one raw s_barrier -- it cannot cross the asm-"memory" waitcnts).
// Write lands after issue => no reader can observe the overwrite.  The round-0
// 4/4 ring evicted the A-slot read in the SAME phase (timing bet -> absmax 0.125).
// Swizzle (T2): LDS (row, chunk p of 16B) holds global chunk p ^ s(row),
// s(r) = (r&3)^((r>>2)&3); source is pre-swizzled since global_load_lds dest must
// be linear (guide rule 21).  Per-bank load is exactly balanced (8 lanes/group).
// EPI: 0 = bf16 store, 1 = fp32 store + fp32 residual(aux), 2 = exact-GELU -> bf16,
//      3 = multiply by existing bf16 in C -> bf16
template<int EPI>
__global__ __launch_bounds__(512, 2) void k_gemm(const short* __restrict__ A,
                                                 const short* __restrict__ Bt,
                                                 void* Cv, const void* aux,
                                                 int M, int N, int K) {
  __shared__ __align__(16) short As[5 * 256 * 32];
  __shared__ __align__(16) short Bs[4 * 256 * 32];
  const int tiles_n = gridDim.x;
  const int nwg = tiles_n * (int)gridDim.y;
  int bid = (int)blockIdx.y * tiles_n + (int)blockIdx.x;
  if ((nwg & 7) == 0) bid = (bid & 7) * (nwg >> 3) + (bid >> 3);   // XCD swizzle
  const int m_tile = bid / tiles_n, n_tile = bid - m_tile * tiles_n;
  const int m0 = m_tile << 8, n0 = n_tile << 8;

  const int tid = threadIdx.x;
  const int wave = tid >> 6, lane = tid & 63;
  const int ll = lane & 15, lh = lane >> 4;
  const int wm = wave >> 2, wn = wave & 3;

  // staging geometry: thread tid covers LDS row sr0 (+128 for 2nd load), chunk tid&3
  const int sr0 = tid >> 2;
  const int g = (tid & 3) ^ ((sr0 & 3) ^ ((sr0 >> 2) & 3));  // pre-swizzled src chunk
  const short* Ag0 = A  + (size_t)(m0 + sr0) * K + g * 8;
  const short* Bg0 = Bt + (size_t)(n0 + sr0) * K + g * 8;
  const size_t rstep = (size_t)128 * K;
  const int wuB = wave << 9;                                  // wave*512 shorts

  const int NKT = K >> 6;
  const int HMAX = NKT << 2;

  auto STAGE = [&](int h) {
    if (h > HMAX - 1) h = HMAX - 1;                 // tail clamp (idempotent)
    const int sidx = h >> 1;                        // 2*tile + khalf
    const int koff = ((h >> 2) << 6) + (((h >> 1) & 1) << 5);
    if ((h & 1) == 0) {                             // A half-tile, 5-ring
      const int sl = (sidx % 5) << 13;
      __builtin_amdgcn_global_load_lds((gas_ptr)(Ag0 + koff),
                                       (las_ptr)(As + sl + wuB), 16, 0, 0);
      __builtin_amdgcn_global_load_lds((gas_ptr)(Ag0 + koff + rstep),
                                       (las_ptr)(As + sl + 4096 + wuB), 16, 0, 0);
    } else {                                        // B half-tile, 4-ring
      const int sl = (sidx & 3) << 13;
      __builtin_amdgcn_global_load_lds((gas_ptr)(Bg0 + koff),
                                       (las_ptr)(Bs + sl + wuB), 16, 0, 0);
      __builtin_amdgcn_global_load_lds((gas_ptr)(Bg0 + koff + rstep),
                                       (las_ptr)(Bs + sl + 4096 + wuB), 16, 0, 0);
    }
  };

  const f32x4 fz = {0.f, 0.f, 0.f, 0.f};
  f32x4 acc[8][4];
  #pragma unroll
  for (int i = 0; i < 8; ++i)
    #pragma unroll
    for (int j = 0; j < 4; ++j) acc[i][j] = fz;

  // reader offsets: row = (wm*128|wn*64) + f*16 + ll, chunk = lh ^ s(row) = lh ^ sA
  const int sA = (ll & 3) ^ ((ll >> 2) & 3);
  const int cOff = (lh ^ sA) << 3;
  const int rdA = (((wm << 7) + ll) << 5) + cOff;
  const int rdB = (((wn << 6) + ll) << 5) + cOff;

  // prologue: 7 half-tiles issued (tile0 complete + 3 in flight: h4,h5,h6)
  #pragma unroll
  for (int h = 0; h < 7; ++h) STAGE(h);
  asm volatile("s_waitcnt vmcnt(6)" ::: "memory");
  __builtin_amdgcn_s_barrier();

  for (int kt = 0; kt < NKT; ++kt) {
    const int hb = (kt << 2) + 7;
    const int slA0 = ((2 * kt) % 5) << 13;       // A slot of (kt, kh0)
    const int slA1 = ((2 * kt + 1) % 5) << 13;   // A slot of (kt, kh1)
    const int slB0 = ((2 * kt) & 3) << 13;       // B slot of (kt, kh0)
    const int slB1 = slB0 + (1 << 13);           // B slot of (kt, kh1)
    bf16x8 bA[4], bB[4];

    // ---- phase 0: kc0, mf0-3 ----
    #pragma unroll
    for (int nf = 0; nf < 4; ++nf) bB[nf] = *(const bf16x8*)&Bs[slB0 + rdB + nf * 512];
    #pragma unroll
    for (int mf = 0; mf < 4; ++mf) bA[mf] = *(const bf16x8*)&As[slA0 + rdA + mf * 512];
    STAGE(hb);
    __builtin_amdgcn_s_barrier();
    asm volatile("s_waitcnt lgkmcnt(0)" ::: "memory");
    __builtin_amdgcn_s_setprio(1);
    #pragma unroll
    for (int mf = 0; mf < 4; ++mf)
      #pragma unroll
      for (int nf = 0; nf < 4; ++nf)
        acc[mf][nf] = __builtin_amdgcn_mfma_f32_16x16x32_bf16(bA[mf], bB[nf], acc[mf][nf], 0, 0, 0);
    __builtin_amdgcn_s_setprio(0);
    __builtin_amdgcn_s_barrier();

    // ---- phase 1: kc0, mf4-7 ----
    #pragma unroll
    for (int mf = 0; mf < 4; ++mf) bA[mf] = *(const bf16x8*)&As[slA0 + rdA + 2048 + mf * 512];
    STAGE(hb + 1);
    __builtin_amdgcn_s_barrier();
    asm volatile("s_waitcnt lgkmcnt(0)" ::: "memory");
    __builtin_amdgcn_s_setprio(1);
    #pragma unroll
    for (int mf = 0; mf < 4; ++mf)
      #pragma unroll
      for (int nf = 0; nf < 4; ++nf)
        acc[4 + mf][nf] = __builtin_amdgcn_mfma_f32_16x16x32_bf16(bA[mf], bB[nf], acc[4 + mf][nf], 0, 0, 0);
    __builtin_amdgcn_s_setprio(0);
    __builtin_amdgcn_s_barrier();

    // ---- phase 2: kc1, mf0-3 ----
    #pragma unroll
    for (int nf = 0; nf < 4; ++nf) bB[nf] = *(const bf16x8*)&Bs[slB1 + rdB + nf * 512];
    #pragma unroll
    for (int mf = 0; mf < 4; ++mf) bA[mf] = *(const bf16x8*)&As[slA1 + rdA + mf * 512];
    STAGE(hb + 2);
    __builtin_amdgcn_s_barrier();
    asm volatile("s_waitcnt lgkmcnt(0)" ::: "memory");
    __builtin_amdgcn_s_setprio(1);
    #pragma unroll
    for (int mf = 0; mf < 4; ++mf)
      #pragma unroll
      for (int nf = 0; nf < 4; ++nf)
        acc[mf][nf] = __builtin_amdgcn_mfma_f32_16x16x32_bf16(bA[mf], bB[nf], acc[mf][nf], 0, 0, 0);
    __builtin_amdgcn_s_setprio(0);
    __builtin_amdgcn_s_barrier();

    // ---- phase 3: kc1, mf4-7 (+ the one counted wait per K-tile) ----
    #pragma unroll
    for (int mf = 0; mf < 4; ++mf) bA[mf] = *(const bf16x8*)&As[slA1 + rdA + 2048 + mf * 512];
    STAGE(hb + 3);
    __builtin_amdgcn_s_barrier();
    asm volatile("s_waitcnt lgkmcnt(0)" ::: "memory");
    __builtin_amdgcn_s_setprio(1);
    #pragma unroll
    for (int mf = 0; mf < 4; ++mf)
      #pragma unroll
      for (int nf = 0; nf < 4; ++nf)
        acc[4 + mf][nf] = __builtin_amdgcn_mfma_f32_16x16x32_bf16(bA[mf], bB[nf], acc[4 + mf][nf], 0, 0, 0);
    __builtin_amdgcn_s_setprio(0);
    asm volatile("s_waitcnt vmcnt(6)" ::: "memory");   // next K-tile fully landed
    __builtin_amdgcn_s_barrier();
  }

  // epilogue; verified C/D layout: col = lane&15, row = (lane>>4)*4 + reg
  #pragma unroll
  for (int mf = 0; mf < 8; ++mf) {
    const int row = m0 + (wm << 7) + (mf << 4) + (lh << 2);
    #pragma unroll
    for (int nf = 0; nf < 4; ++nf) {
      const int col = n0 + (wn << 6) + (nf << 4) + ll;
      #pragma unroll
      for (int rg = 0; rg < 4; ++rg) {
        const float c = acc[mf][nf][rg];
        const size_t idx = (size_t)(row + rg) * N + col;
        if constexpr (EPI == 0) {
          ((short*)Cv)[idx] = f2bf(c);
        } else if constexpr (EPI == 1) {
          ((float*)Cv)[idx] = c + ((const float*)aux)[idx];
        } else if constexpr (EPI == 2) {
          float gl = 0.5f * c * (1.0f + erff(c * 0.70710678118654752f));
          ((short*)Cv)[idx] = f2bf(gl);
        } else {
          float gl = bf2f(((short*)Cv)[idx]);
          ((short*)Cv)[idx] = f2bf(c * gl);
        }
      }
    }
  }
}

// ---------------- flash attention ----------------
#define CEXP 0.12752682475470602f   // log2(e)/sqrt(128)
__global__ __launch_bounds__(256, 2) void k_flash(const short* __restrict__ qkv,
                                                  const short* __restrict__ vt,
                                                  short* __restrict__ attn) {
  __shared__ short Kt[64][136];
  __shared__ short VtT[128][72];
  __shared__ short Pt[4][32][72];
  const int qt = blockIdx.x, bh = blockIdx.y;
  const int b = bh >> 4, h = bh & 15;
  const int q0 = qt << 7;
  const int tid = threadIdx.x, wave = tid >> 6, lane = tid & 63;
  const int ll = lane & 15, lh = lane >> 4;
  const short* qbase = qkv + (size_t)b * S_ * QKVN + h * DH_;
  const short* kbase = qbase + E_;
  const short* vbase = vt + (size_t)bh * DH_ * S_;

  bf16x8 qf[2][4];
  #pragma unroll
  for (int mt = 0; mt < 2; ++mt) {
    const short* qr = qbase + (size_t)(q0 + wave * 32 + mt * 16 + ll) * QKVN;
    #pragma unroll
    for (int kc = 0; kc < 4; ++kc) qf[mt][kc] = *(const bf16x8*)(qr + kc * 32 + lh * 8);
  }

  const f32x4 fzero = {0.f, 0.f, 0.f, 0.f};
  float m_i[2][4], l_i[2][4];
  f32x4 oacc[2][8];
  #pragma unroll
  for (int mt = 0; mt < 2; ++mt) {
    #pragma unroll
    for (int rg = 0; rg < 4; ++rg) { m_i[mt][rg] = -1e30f; l_i[mt][rg] = 0.f; }
    #pragma unroll
    for (int n8 = 0; n8 < 8; ++n8) oacc[mt][n8] = fzero;
  }

  const int nkt = (q0 + 128) >> 6;
  for (int kt = 0; kt < nkt; ++kt) {
    const int k0 = kt << 6;
    __syncthreads();
    #pragma unroll
    for (int p = 0; p < 4; ++p) {
      int idx = p * 256 + tid;
      int r = idx >> 4, c0 = (idx & 15) << 3;
      *(s16x8*)&Kt[r][c0] = *(const s16x8*)(kbase + (size_t)(k0 + r) * QKVN + c0);
      int dh = idx >> 3, kk = (idx & 7) << 3;
      *(s16x8*)&VtT[dh][kk] = *(const s16x8*)(vbase + (size_t)dh * S_ + k0 + kk);
    }
    __syncthreads();

    f32x4 sc[2][4];
    #pragma unroll
    for (int mt = 0; mt < 2; ++mt)
      #pragma unroll
      for (int nt = 0; nt < 4; ++nt) sc[mt][nt] = fzero;
    #pragma unroll
    for (int kc = 0; kc < 4; ++kc) {
      bf16x8 kb[4];
      #pragma unroll
      for (int nt = 0; nt < 4; ++nt)
        kb[nt] = *(const bf16x8*)&Kt[nt * 16 + ll][kc * 32 + lh * 8];
      #pragma unroll
      for (int mt = 0; mt < 2; ++mt)
        #pragma unroll
        for (int nt = 0; nt < 4; ++nt)
          sc[mt][nt] = __builtin_amdgcn_mfma_f32_16x16x32_bf16(qf[mt][kc], kb[nt], sc[mt][nt], 0, 0, 0);
    }

    if (k0 + 63 > q0) {
      #pragma unroll
      for (int mt = 0; mt < 2; ++mt)
        #pragma unroll
        for (int nt = 0; nt < 4; ++nt)
          #pragma unroll
          for (int rg = 0; rg < 4; ++rg) {
            int kidx = k0 + nt * 16 + ll;
            int qidx = q0 + wave * 32 + mt * 16 + lh * 4 + rg;
            if (kidx > qidx) sc[mt][nt][rg] = -1e30f;
          }
    }

    #pragma unroll
    for (int mt = 0; mt < 2; ++mt)
      #pragma unroll
      for (int rg = 0; rg < 4; ++rg) {
        float mx = fmaxf(fmaxf(sc[mt][0][rg], sc[mt][1][rg]),
                         fmaxf(sc[mt][2][rg], sc[mt][3][rg]));
        #pragma unroll
        for (int off = 1; off < 16; off <<= 1) mx = fmaxf(mx, __shfl_xor(mx, off, 64));
        float mn = fmaxf(m_i[mt][rg], mx);
        float al = exp2f((m_i[mt][rg] - mn) * CEXP);
        m_i[mt][rg] = mn;
        float rsum = 0.f;
        #pragma unroll
        for (int nt = 0; nt < 4; ++nt) {
          float pv = exp2f((sc[mt][nt][rg] - mn) * CEXP);
          sc[mt][nt][rg] = pv;
          rsum += pv;
        }
        #pragma unroll
        for (int off = 1; off < 16; off <<= 1) rsum += __shfl_xor(rsum, off, 64);
        l_i[mt][rg] = l_i[mt][rg] * al + rsum;
        #pragma unroll
        for (int n8 = 0; n8 < 8; ++n8) oacc[mt][n8][rg] *= al;
      }

    #pragma unroll
    for (int mt = 0; mt < 2; ++mt)
      #pragma unroll
      for (int nt = 0; nt < 4; ++nt)
        #pragma unroll
        for (int rg = 0; rg < 4; ++rg)
          Pt[wave][mt * 16 + lh * 4 + rg][nt * 16 + ll] = f2bf(sc[mt][nt][rg]);

    #pragma unroll
    for (int kc2 = 0; kc2 < 2; ++kc2) {
      bf16x8 pa[2];
      #pragma unroll
      for (int mt = 0; mt < 2; ++mt)
        pa[mt] = *(const bf16x8*)&Pt[wave][mt * 16 + ll][kc2 * 32 + lh * 8];
      #pragma unroll
      for (int n8 = 0; n8 < 8; ++n8) {
        bf16x8 vb = *(const bf16x8*)&VtT[n8 * 16 + ll][kc2 * 32 + lh * 8];
        #pragma unroll
        for (int mt = 0; mt < 2; ++mt)
          oacc[mt][n8] = __builtin_amdgcn_mfma_f32_16x16x32_bf16(pa[mt], vb, oacc[mt][n8], 0, 0, 0);
      }
    }
  }

  short* ab = attn + (size_t)(b * S_) * E_ + h * DH_;
  #pragma unroll
  for (int mt = 0; mt < 2; ++mt) {
    const int row = q0 + wave * 32 + mt * 16 + lh * 4;
    #pragma unroll
    for (int n8 = 0; n8 < 8; ++n8) {
      const int col = n8 * 16 + ll;
      #pragma unroll
      for (int rg = 0; rg < 4; ++rg)
        ab[(size_t)(row + rg) * E_ + col] = f2bf(oacc[mt][n8][rg] / l_i[mt][rg]);
    }
  }
}

// ---------------- launch ----------------
// Workspace plan (192 MiB; single stream => lifetime-disjoint aliasing is safe):
//   W slot   [ 33,554,432 B]  each weight transposed here right before its GEMM
//   big slot [134,217,728 B]  phase 1: QKV | VT; phase 2: Hb
//   act slot [ 33,554,432 B]  Y1 -> ATTN -> Y2
//   X2 (fp32 residual stream) lives in d_out, overwritten by the final GEMM.
extern "C" void kernel_launch(void* const* d_in, const int* in_sizes, int n_in,
                              void* d_out, int out_size, void* d_ws, size_t ws_size,
                              hipStream_t stream) {
  (void)in_sizes; (void)n_in; (void)out_size; (void)ws_size;
  const float* x      = (const float*)d_in[0];
  const float* g_attn = (const float*)d_in[1];
  const float* g_ffn  = (const float*)d_in[2];
  const float* wq     = (const float*)d_in[3];
  const float* wk     = (const float*)d_in[4];
  const float* wv     = (const float*)d_in[5];
  const float* wo     = (const float*)d_in[6];
  const float* wg     = (const float*)d_in[7];
  const float* wl     = (const float*)d_in[8];
  const float* wout   = (const float*)d_in[9];
  const int*   pos    = (const int*)d_in[10];

  char* wsb = (char*)d_ws;
  short* W    = (short*)wsb;
  short* BIG  = (short*)(wsb + (size_t)33554432);
  short* ACT  = (short*)(wsb + (size_t)33554432 + 134217728);

  short* QKV  = BIG;
  short* VT   = BIG + (size_t)NTOK * QKVN;
  short* Hb   = BIG;
  short* Y1   = ACT;
  short* ATTN = ACT;
  short* Y2   = ACT;
  float* X2   = (float*)d_out;

  const dim3 blk(256);
  const dim3 gblk(512);

  k_transpose_f32_bf16<<<dim3(64, 64), blk, 0, stream>>>(wq, W,                   2048, 2048);
  k_transpose_f32_bf16<<<dim3(64, 64), blk, 0, stream>>>(wk, W + 2048 * 2048,     2048, 2048);
  k_transpose_f32_bf16<<<dim3(64, 64), blk, 0, stream>>>(wv, W + 2 * 2048 * 2048, 2048, 2048);

  k_rms_rope<<<NTOK, blk, 0, stream>>>(x, g_attn, pos, Y1);
  k_gemm<0><<<dim3(QKVN / 256, NTOK / 256), gblk, 0, stream>>>(Y1, W, QKV, nullptr, NTOK, QKVN, E_);
  k_transpose_v<<<dim3(S_ / 32, DH_ / 32, B_ * H_), blk, 0, stream>>>(QKV, VT);
  k_flash<<<dim3(S_ / 128, B_ * H_), blk, 0, stream>>>(QKV, VT, ATTN);

  k_transpose_f32_bf16<<<dim3(64, 64), blk, 0, stream>>>(wo, W, 2048, 2048);
  k_gemm<1><<<dim3(E_ / 256, NTOK / 256), gblk, 0, stream>>>(ATTN, W, X2, x, NTOK, E_, E_);

  k_rms<<<NTOK, blk, 0, stream>>>(X2, g_ffn, Y2);

  k_transpose_f32_bf16<<<dim3(256, 64), blk, 0, stream>>>(wg, W, 2048, 8192);
  k_gemm<2><<<dim3(F_ / 256, NTOK / 256), gblk, 0, stream>>>(Y2, W, Hb, nullptr, NTOK, F_, E_);
  k_transpose_f32_bf16<<<dim3(256, 64), blk, 0, stream>>>(wl, W, 2048, 8192);
  k_gemm<3><<<dim3(F_ / 256, NTOK / 256), gblk, 0, stream>>>(Y2, W, Hb, nullptr, NTOK, F_, E_);
  k_transpose_f32_bf16<<<dim3(64, 256), blk, 0, stream>>>(wout, W, 8192, 2048);
  k_gemm<1><<<dim3(E_ / 256, NTOK / 256), gblk, 0, stream>>>(Hb, W, d_out, X2, NTOK, E_, F_);
}

// Round 3
// 2032.186 us; speedup vs baseline: 1.0394x; 1.0394x over previous
//
#include <hip/hip_runtime.h>
#include <cstdint>
#include <cstddef>

#define B_ 4
#define S_ 2048
#define E_ 2048
#define H_ 16
#define DH_ 128
#define F_ 8192
#define NTOK (B_*S_)
#define QKVN (3*E_)

typedef __attribute__((ext_vector_type(4))) float f32x4;
typedef __attribute__((ext_vector_type(8))) __bf16 bf16x8;
typedef __attribute__((ext_vector_type(8))) short s16x8;
typedef __attribute__((ext_vector_type(4))) short s16x4;

using gas_ptr = const __attribute__((address_space(1))) void*;
using las_ptr = __attribute__((address_space(3))) void*;

__device__ __forceinline__ short f2bf(float f) {
  union { float f; uint32_t u; } v{f};
  uint32_t r = v.u + 0x7FFFu + ((v.u >> 16) & 1u);   // round-to-nearest-even
  return (short)(r >> 16);
}
__device__ __forceinline__ float bf2f(short s) {
  union { uint32_t u; float f; } v;
  v.u = ((uint32_t)(uint16_t)s) << 16;
  return v.f;
}

// ---------------- RMSNorm + RoPE -> bf16 ----------------
__global__ __launch_bounds__(256) void k_rms_rope(const float* __restrict__ x,
                                                  const float* __restrict__ gamma,
                                                  const int* __restrict__ pos,
                                                  short* __restrict__ y) {
  const int row = blockIdx.x;
  const int s = row & (S_ - 1);
  const int t = threadIdx.x;
  const int head = t >> 4;
  const int j0 = (t & 15) << 2;
  const float* xr = x + (size_t)row * E_;
  const int c1 = head * DH_ + j0;
  const int c2 = c1 + 64;
  f32x4 x1 = *(const f32x4*)(xr + c1);
  f32x4 x2 = *(const f32x4*)(xr + c2);
  float ss = x1[0]*x1[0]+x1[1]*x1[1]+x1[2]*x1[2]+x1[3]*x1[3]
           + x2[0]*x2[0]+x2[1]*x2[1]+x2[2]*x2[2]+x2[3]*x2[3];
  #pragma unroll
  for (int off = 32; off >= 1; off >>= 1) ss += __shfl_xor(ss, off, 64);
  __shared__ float red[4];
  __shared__ float rsh;
  if ((t & 63) == 0) red[t >> 6] = ss;
  __syncthreads();
  if (t == 0) rsh = rsqrtf((red[0]+red[1]+red[2]+red[3]) * (1.0f / E_) + 1e-5f);
  __syncthreads();
  const float r = rsh;
  f32x4 g1 = *(const f32x4*)(gamma + c1);
  f32x4 g2 = *(const f32x4*)(gamma + c2);
  const float p = (float)pos[s];
  s16x4 o1, o2;
  #pragma unroll
  for (int jj = 0; jj < 4; ++jj) {
    float fi = exp2f((float)(j0 + jj) * (-13.287712379549449f / 64.0f));
    float ang = p * fi;
    float sn, cs;
    sincosf(ang, &sn, &cs);
    float a = x1[jj] * r * g1[jj];
    float b = x2[jj] * r * g2[jj];
    o1[jj] = f2bf(a * cs - b * sn);
    o2[jj] = f2bf(b * cs + a * sn);
  }
  *(s16x4*)(y + (size_t)row * E_ + c1) = o1;
  *(s16x4*)(y + (size_t)row * E_ + c2) = o2;
}

// ---------------- RMSNorm (no rope), fp32 in -> bf16 ----------------
__global__ __launch_bounds__(256) void k_rms(const float* __restrict__ x,
                                             const float* __restrict__ gamma,
                                             short* __restrict__ y) {
  const int row = blockIdx.x;
  const int t = threadIdx.x;
  const int c = t << 3;
  const float* xr = x + (size_t)row * E_;
  f32x4 a = *(const f32x4*)(xr + c);
  f32x4 b = *(const f32x4*)(xr + c + 4);
  float ss = a[0]*a[0]+a[1]*a[1]+a[2]*a[2]+a[3]*a[3]
           + b[0]*b[0]+b[1]*b[1]+b[2]*b[2]+b[3]*b[3];
  #pragma unroll
  for (int off = 32; off >= 1; off >>= 1) ss += __shfl_xor(ss, off, 64);
  __shared__ float red[4];
  __shared__ float rsh;
  if ((t & 63) == 0) red[t >> 6] = ss;
  __syncthreads();
  if (t == 0) rsh = rsqrtf((red[0]+red[1]+red[2]+red[3]) * (1.0f / E_) + 1e-5f);
  __syncthreads();
  const float r = rsh;
  f32x4 ga = *(const f32x4*)(gamma + c);
  f32x4 gb = *(const f32x4*)(gamma + c + 4);
  s16x8 o;
  #pragma unroll
  for (int jj = 0; jj < 4; ++jj) {
    o[jj]   = f2bf(a[jj] * r * ga[jj]);
    o[4+jj] = f2bf(b[jj] * r * gb[jj]);
  }
  *(s16x8*)(y + (size_t)row * E_ + c) = o;
}

// ---------------- fp32 (R,C) -> bf16 (C,R) transpose ----------------
__global__ __launch_bounds__(256) void k_transpose_f32_bf16(const float* __restrict__ src,
                                                            short* __restrict__ dst,
                                                            int R, int C) {
  __shared__ float tile[32][33];
  const int c0 = blockIdx.x << 5, r0 = blockIdx.y << 5;
  const int tx = threadIdx.x & 31, ty = threadIdx.x >> 5;
  #pragma unroll
  for (int j = 0; j < 32; j += 8)
    tile[ty + j][tx] = src[(size_t)(r0 + ty + j) * C + c0 + tx];
  __syncthreads();
  #pragma unroll
  for (int j = 0; j < 32; j += 8)
    dst[(size_t)(c0 + ty + j) * R + r0 + tx] = f2bf(tile[tx][ty + j]);
}

// ---------------- V section of QKV -> per-(b,h) V^T (bf16) ----------------
__global__ __launch_bounds__(256) void k_transpose_v(const short* __restrict__ qkv,
                                                     short* __restrict__ vt) {
  __shared__ short tile[32][33];
  const int bh = blockIdx.z;
  const short* src = qkv + (size_t)(bh >> 4) * S_ * QKVN + 2 * E_ + (bh & 15) * DH_;
  short* dst = vt + (size_t)bh * DH_ * S_;
  const int s0 = blockIdx.x << 5, d0 = blockIdx.y << 5;
  const int tx = threadIdx.x & 31, ty = threadIdx.x >> 5;
  #pragma unroll
  for (int j = 0; j < 32; j += 8)
    tile[ty + j][tx] = src[(size_t)(s0 + ty + j) * QKVN + d0 + tx];
  __syncthreads();
  #pragma unroll
  for (int j = 0; j < 32; j += 8)
    dst[(size_t)(d0 + ty + j) * S_ + s0 + tx] = tile[tx][ty + j];
}

// ---------------- 256x256-tile 8-phase bf16 GEMM, m201 LDS geometry ----------------
// C[M,N] = A[M,K] * Bt[N,K]^T.  512 threads = 8 waves (2M x 4N); per-wave output
// 128x64 = acc[8][4].  BK=64 (one slot holds all 64 K-cols: row = 128 B).
// ROUND-2 POST-MORTEM: [256][32] slots (64B rows) + 4-chunk XOR measured 2.5e7
// LDS bank conflicts (+4 cy per ds_read_b128 -> LDS-read-bound, MfmaUtil 25%).
// This version copies m201's MEASURED-conflict-free geometry verbatim:
// slot = [128 rows][64 cols] bf16 (16 KiB), st_16x32 swizzle
//   byte' = byte ^ (((byte>>9)&1)<<5)   i.e.  col_byte ^= ((row>>2)&1)<<5.
// global_load_lds dest stays LINEAR; the SOURCE is inverse-swizzled (rule 21):
// thread tid writes LDS offset tid*16B of a 64-row block -> reads global
// (row = tid>>3, chunk16B = (tid&7) ^ (((tid>>5)&1)<<1)).  Element-trace:
//   tid=42,j0: chunk=0 -> src row 5 cols 0..7; LDS o=672 -> r=5, cb=0.
//   reader (ll=5,lh=0,kc=0): o' = 5*128 + (0 ^ 32)... reads row5 logical cols 0..7. OK
// Rings: A = 5 slots (80 KiB), B = 4 slots (64 KiB); slot = (2t+half) mod ring.
// Stage order per tile t: p0 A-hi(t+1), p1 B-lo(t+1), p2 B-hi(t+1), p3 A-lo(t+2);
// every eviction targets a slot whose last ds_read completed >= 4 barriers before
// the stage issues (race-free by barrier order).  Tail stages clamp tile to
// NKT-1: byte-identical re-issue = benign.  Tile-boundary wait = vmcnt(2)
// (3 halves retired, A-lo(t+2) kept in flight -> never drains to 0; T3+T4).
// T5 setprio(1) around each 16-MFMA cluster.
// EPI: 0 = bf16 store, 1 = fp32 store + fp32 residual(aux), 2 = exact-GELU -> bf16,
//      3 = multiply by existing bf16 in C -> bf16
template<int EPI>
__global__ __launch_bounds__(512, 2) void k_gemm(const short* __restrict__ A,
                                                 const short* __restrict__ Bt,
                                                 void* Cv, const void* aux,
                                                 int M, int N, int K) {
  __shared__ __align__(16) short As[5 * 128 * 64];
  __shared__ __align__(16) short Bs[4 * 128 * 64];
  const int tiles_n = gridDim.x;
  const int nwg = tiles_n * (int)gridDim.y;
  int bid = (int)blockIdx.y * tiles_n + (int)blockIdx.x;
  if ((nwg & 7) == 0) bid = (bid & 7) * (nwg >> 3) + (bid >> 3);   // XCD swizzle
  const int m_tile = bid / tiles_n, n_tile = bid - m_tile * tiles_n;
  const int m0 = m_tile << 8, n0 = n_tile << 8;

  const int tid = threadIdx.x;
  const int wave = tid >> 6, lane = tid & 63;
  const int ll = lane & 15, lh = lane >> 4;
  const int wm = wave >> 2, wn = wave & 3;

  // ---- staging geometry (inverse-st_16x32 source) ----
  const int sr = tid >> 3;                                   // row 0..63 in block
  const int chk = (tid & 7) ^ (((tid >> 5) & 1) << 1);       // 16B chunk, pre-swizzled
  const short* Ag0 = A  + (size_t)(m0 + sr) * K + chk * 8;
  const short* Bg0 = Bt + (size_t)(n0 + sr) * K + chk * 8;
  const int wuB = wave << 9;                                 // wave*1024 B in shorts

  const int NKT = K >> 6;

  auto STAGE_A = [&](int t2, int half) {
    if (t2 > NKT - 1) t2 = NKT - 1;                          // tail clamp (idempotent)
    const int sl = ((2 * t2 + half) % 5) << 13;              // slot * 8192 shorts
    const short* src = Ag0 + (size_t)(half * 128) * K + t2 * 64;
    __builtin_amdgcn_global_load_lds((gas_ptr)src,
                                     (las_ptr)(As + sl + wuB), 16, 0, 0);
    __builtin_amdgcn_global_load_lds((gas_ptr)(src + (size_t)64 * K),
                                     (las_ptr)(As + sl + 4096 + wuB), 16, 0, 0);
  };
  auto STAGE_B = [&](int t2, int half) {
    if (t2 > NKT - 1) t2 = NKT - 1;
    const int sl = ((2 * t2 + half) & 3) << 13;
    const short* src = Bg0 + (size_t)(half * 128) * K + t2 * 64;
    __builtin_amdgcn_global_load_lds((gas_ptr)src,
                                     (las_ptr)(Bs + sl + wuB), 16, 0, 0);
    __builtin_amdgcn_global_load_lds((gas_ptr)(src + (size_t)64 * K),
                                     (las_ptr)(Bs + sl + 4096 + wuB), 16, 0, 0);
  };

  const f32x4 fz = {0.f, 0.f, 0.f, 0.f};
  f32x4 acc[8][4];
  #pragma unroll
  for (int i = 0; i < 8; ++i)
    #pragma unroll
    for (int j = 0; j < 4; ++j) acc[i][j] = fz;

  // ---- reader offsets (shorts, within slot) ----
  // row r in slot: A: mf*16+ll  (wave wm reads slot 2t+wm);  B: (wn&1)*64+nf*16+ll
  // col: (kc*32 + lh*8) ^ swsh,  swsh = ((ll>>2)&1)*16  (st_16x32, 16 sh = 32 B)
  const int swsh = ((ll >> 2) & 1) << 4;
  const int c0s = (lh << 3) ^ swsh;            // kc = 0
  const int c1s = (32 + (lh << 3)) ^ swsh;     // kc = 1
  const int rAb = (ll << 6);                   // + mf*1024
  const int rBb = ((wn & 1) << 12) + (ll << 6);// + nf*1024

  // ---- prologue: tile0 all 4 halves + A-lo(1); wait tile0 (vmcnt(2)) ----
  STAGE_A(0, 0); STAGE_A(0, 1); STAGE_B(0, 0); STAGE_B(0, 1); STAGE_A(1, 0);
  asm volatile("s_waitcnt vmcnt(2)" ::: "memory");
  __builtin_amdgcn_s_barrier();

  for (int kt = 0; kt < NKT; ++kt) {
    const int slA = ((2 * kt + wm) % 5) << 13;
    const int slB = ((2 * kt + (wn >> 1)) & 3) << 13;
    bf16x8 bA[4], bB[4];

    // ---- phase 0: kc0, mf0-3 ----
    #pragma unroll
    for (int nf = 0; nf < 4; ++nf) bB[nf] = *(const bf16x8*)&Bs[slB + rBb + nf * 1024 + c0s];
    #pragma unroll
    for (int mf = 0; mf < 4; ++mf) bA[mf] = *(const bf16x8*)&As[slA + rAb + mf * 1024 + c0s];
    STAGE_A(kt + 1, 1);
    __builtin_amdgcn_s_barrier();
    asm volatile("s_waitcnt lgkmcnt(0)" ::: "memory");
    __builtin_amdgcn_s_setprio(1);
    #pragma unroll
    for (int mf = 0; mf < 4; ++mf)
      #pragma unroll
      for (int nf = 0; nf < 4; ++nf)
        acc[mf][nf] = __builtin_amdgcn_mfma_f32_16x16x32_bf16(bA[mf], bB[nf], acc[mf][nf], 0, 0, 0);
    __builtin_amdgcn_s_setprio(0);
    __builtin_amdgcn_s_barrier();

    // ---- phase 1: kc0, mf4-7 ----
    #pragma unroll
    for (int mf = 0; mf < 4; ++mf) bA[mf] = *(const bf16x8*)&As[slA + rAb + (mf + 4) * 1024 + c0s];
    STAGE_B(kt + 1, 0);
    __builtin_amdgcn_s_barrier();
    asm volatile("s_waitcnt lgkmcnt(0)" ::: "memory");
    __builtin_amdgcn_s_setprio(1);
    #pragma unroll
    for (int mf = 0; mf < 4; ++mf)
      #pragma unroll
      for (int nf = 0; nf < 4; ++nf)
        acc[4 + mf][nf] = __builtin_amdgcn_mfma_f32_16x16x32_bf16(bA[mf], bB[nf], acc[4 + mf][nf], 0, 0, 0);
    __builtin_amdgcn_s_setprio(0);
    __builtin_amdgcn_s_barrier();

    // ---- phase 2: kc1, mf0-3 ----
    #pragma unroll
    for (int nf = 0; nf < 4; ++nf) bB[nf] = *(const bf16x8*)&Bs[slB + rBb + nf * 1024 + c1s];
    #pragma unroll
    for (int mf = 0; mf < 4; ++mf) bA[mf] = *(const bf16x8*)&As[slA + rAb + mf * 1024 + c1s];
    STAGE_B(kt + 1, 1);
    __builtin_amdgcn_s_barrier();
    asm volatile("s_waitcnt lgkmcnt(0)" ::: "memory");
    __builtin_amdgcn_s_setprio(1);
    #pragma unroll
    for (int mf = 0; mf < 4; ++mf)
      #pragma unroll
      for (int nf = 0; nf < 4; ++nf)
        acc[mf][nf] = __builtin_amdgcn_mfma_f32_16x16x32_bf16(bA[mf], bB[nf], acc[mf][nf], 0, 0, 0);
    __builtin_amdgcn_s_setprio(0);
    __builtin_amdgcn_s_barrier();

    // ---- phase 3: kc1, mf4-7 (+ the one counted wait per K-tile) ----
    #pragma unroll
    for (int mf = 0; mf < 4; ++mf) bA[mf] = *(const bf16x8*)&As[slA + rAb + (mf + 4) * 1024 + c1s];
    STAGE_A(kt + 2, 0);
    __builtin_amdgcn_s_barrier();
    asm volatile("s_waitcnt lgkmcnt(0)" ::: "memory");
    __builtin_amdgcn_s_setprio(1);
    #pragma unroll
    for (int mf = 0; mf < 4; ++mf)
      #pragma unroll
      for (int nf = 0; nf < 4; ++nf)
        acc[4 + mf][nf] = __builtin_amdgcn_mfma_f32_16x16x32_bf16(bA[mf], bB[nf], acc[4 + mf][nf], 0, 0, 0);
    __builtin_amdgcn_s_setprio(0);
    asm volatile("s_waitcnt vmcnt(2)" ::: "memory");   // tile kt+1 fully landed
    __builtin_amdgcn_s_barrier();
  }

  // epilogue; verified C/D layout: col = lane&15, row = (lane>>4)*4 + reg
  #pragma unroll
  for (int mf = 0; mf < 8; ++mf) {
    const int row = m0 + (wm << 7) + (mf << 4) + (lh << 2);
    #pragma unroll
    for (int nf = 0; nf < 4; ++nf) {
      const int col = n0 + (wn << 6) + (nf << 4) + ll;
      #pragma unroll
      for (int rg = 0; rg < 4; ++rg) {
        const float c = acc[mf][nf][rg];
        const size_t idx = (size_t)(row + rg) * N + col;
        if constexpr (EPI == 0) {
          ((short*)Cv)[idx] = f2bf(c);
        } else if constexpr (EPI == 1) {
          ((float*)Cv)[idx] = c + ((const float*)aux)[idx];
        } else if constexpr (EPI == 2) {
          float gl = 0.5f * c * (1.0f + erff(c * 0.70710678118654752f));
          ((short*)Cv)[idx] = f2bf(gl);
        } else {
          float gl = bf2f(((short*)Cv)[idx]);
          ((short*)Cv)[idx] = f2bf(c * gl);
        }
      }
    }
  }
}

// ---------------- flash attention ----------------
#define CEXP 0.12752682475470602f   // log2(e)/sqrt(128)
__global__ __launch_bounds__(256, 2) void k_flash(const short* __restrict__ qkv,
                                                  const short* __restrict__ vt,
                                                  short* __restrict__ attn) {
  __shared__ short Kt[64][136];
  __shared__ short VtT[128][72];
  __shared__ short Pt[4][32][72];
  const int qt = blockIdx.x, bh = blockIdx.y;
  const int b = bh >> 4, h = bh & 15;
  const int q0 = qt << 7;
  const int tid = threadIdx.x, wave = tid >> 6, lane = tid & 63;
  const int ll = lane & 15, lh = lane >> 4;
  const short* qbase = qkv + (size_t)b * S_ * QKVN + h * DH_;
  const short* kbase = qbase + E_;
  const short* vbase = vt + (size_t)bh * DH_ * S_;

  bf16x8 qf[2][4];
  #pragma unroll
  for (int mt = 0; mt < 2; ++mt) {
    const short* qr = qbase + (size_t)(q0 + wave * 32 + mt * 16 + ll) * QKVN;
    #pragma unroll
    for (int kc = 0; kc < 4; ++kc) qf[mt][kc] = *(const bf16x8*)(qr + kc * 32 + lh * 8);
  }

  const f32x4 fzero = {0.f, 0.f, 0.f, 0.f};
  float m_i[2][4], l_i[2][4];
  f32x4 oacc[2][8];
  #pragma unroll
  for (int mt = 0; mt < 2; ++mt) {
    #pragma unroll
    for (int rg = 0; rg < 4; ++rg) { m_i[mt][rg] = -1e30f; l_i[mt][rg] = 0.f; }
    #pragma unroll
    for (int n8 = 0; n8 < 8; ++n8) oacc[mt][n8] = fzero;
  }

  const int nkt = (q0 + 128) >> 6;
  for (int kt = 0; kt < nkt; ++kt) {
    const int k0 = kt << 6;
    __syncthreads();
    #pragma unroll
    for (int p = 0; p < 4; ++p) {
      int idx = p * 256 + tid;
      int r = idx >> 4, c0 = (idx & 15) << 3;
      *(s16x8*)&Kt[r][c0] = *(const s16x8*)(kbase + (size_t)(k0 + r) * QKVN + c0);
      int dh = idx >> 3, kk = (idx & 7) << 3;
      *(s16x8*)&VtT[dh][kk] = *(const s16x8*)(vbase + (size_t)dh * S_ + k0 + kk);
    }
    __syncthreads();

    f32x4 sc[2][4];
    #pragma unroll
    for (int mt = 0; mt < 2; ++mt)
      #pragma unroll
      for (int nt = 0; nt < 4; ++nt) sc[mt][nt] = fzero;
    #pragma unroll
    for (int kc = 0; kc < 4; ++kc) {
      bf16x8 kb[4];
      #pragma unroll
      for (int nt = 0; nt < 4; ++nt)
        kb[nt] = *(const bf16x8*)&Kt[nt * 16 + ll][kc * 32 + lh * 8];
      #pragma unroll
      for (int mt = 0; mt < 2; ++mt)
        #pragma unroll
        for (int nt = 0; nt < 4; ++nt)
          sc[mt][nt] = __builtin_amdgcn_mfma_f32_16x16x32_bf16(qf[mt][kc], kb[nt], sc[mt][nt], 0, 0, 0);
    }

    if (k0 + 63 > q0) {
      #pragma unroll
      for (int mt = 0; mt < 2; ++mt)
        #pragma unroll
        for (int nt = 0; nt < 4; ++nt)
          #pragma unroll
          for (int rg = 0; rg < 4; ++rg) {
            int kidx = k0 + nt * 16 + ll;
            int qidx = q0 + wave * 32 + mt * 16 + lh * 4 + rg;
            if (kidx > qidx) sc[mt][nt][rg] = -1e30f;
          }
    }

    #pragma unroll
    for (int mt = 0; mt < 2; ++mt)
      #pragma unroll
      for (int rg = 0; rg < 4; ++rg) {
        float mx = fmaxf(fmaxf(sc[mt][0][rg], sc[mt][1][rg]),
                         fmaxf(sc[mt][2][rg], sc[mt][3][rg]));
        #pragma unroll
        for (int off = 1; off < 16; off <<= 1) mx = fmaxf(mx, __shfl_xor(mx, off, 64));
        float mn = fmaxf(m_i[mt][rg], mx);
        float al = exp2f((m_i[mt][rg] - mn) * CEXP);
        m_i[mt][rg] = mn;
        float rsum = 0.f;
        #pragma unroll
        for (int nt = 0; nt < 4; ++nt) {
          float pv = exp2f((sc[mt][nt][rg] - mn) * CEXP);
          sc[mt][nt][rg] = pv;
          rsum += pv;
        }
        #pragma unroll
        for (int off = 1; off < 16; off <<= 1) rsum += __shfl_xor(rsum, off, 64);
        l_i[mt][rg] = l_i[mt][rg] * al + rsum;
        #pragma unroll
        for (int n8 = 0; n8 < 8; ++n8) oacc[mt][n8][rg] *= al;
      }

    #pragma unroll
    for (int mt = 0; mt < 2; ++mt)
      #pragma unroll
      for (int nt = 0; nt < 4; ++nt)
        #pragma unroll
        for (int rg = 0; rg < 4; ++rg)
          Pt[wave][mt * 16 + lh * 4 + rg][nt * 16 + ll] = f2bf(sc[mt][nt][rg]);

    #pragma unroll
    for (int kc2 = 0; kc2 < 2; ++kc2) {
      bf16x8 pa[2];
      #pragma unroll
      for (int mt = 0; mt < 2; ++mt)
        pa[mt] = *(const bf16x8*)&Pt[wave][mt * 16 + ll][kc2 * 32 + lh * 8];
      #pragma unroll
      for (int n8 = 0; n8 < 8; ++n8) {
        bf16x8 vb = *(const bf16x8*)&VtT[n8 * 16 + ll][kc2 * 32 + lh * 8];
        #pragma unroll
        for (int mt = 0; mt < 2; ++mt)
          oacc[mt][n8] = __builtin_amdgcn_mfma_f32_16x16x32_bf16(pa[mt], vb, oacc[mt][n8], 0, 0, 0);
      }
    }
  }

  short* ab = attn + (size_t)(b * S_) * E_ + h * DH_;
  #pragma unroll
  for (int mt = 0; mt < 2; ++mt) {
    const int row = q0 + wave * 32 + mt * 16 + lh * 4;
    #pragma unroll
    for (int n8 = 0; n8 < 8; ++n8) {
      const int col = n8 * 16 + ll;
      #pragma unroll
      for (int rg = 0; rg < 4; ++rg)
        ab[(size_t)(row + rg) * E_ + col] = f2bf(oacc[mt][n8][rg] / l_i[mt][rg]);
    }
  }
}

// ---------------- launch ----------------
// Workspace plan (192 MiB; single stream => lifetime-disjoint aliasing is safe):
//   W slot   [ 33,554,432 B]  each weight transposed here right before its GEMM
//   big slot [134,217,728 B]  phase 1: QKV | VT; phase 2: Hb
//   act slot [ 33,554,432 B]  Y1 -> ATTN -> Y2
//   X2 (fp32 residual stream) lives in d_out, overwritten by the final GEMM.
extern "C" void kernel_launch(void* const* d_in, const int* in_sizes, int n_in,
                              void* d_out, int out_size, void* d_ws, size_t ws_size,
                              hipStream_t stream) {
  (void)in_sizes; (void)n_in; (void)out_size; (void)ws_size;
  const float* x      = (const float*)d_in[0];
  const float* g_attn = (const float*)d_in[1];
  const float* g_ffn  = (const float*)d_in[2];
  const float* wq     = (const float*)d_in[3];
  const float* wk     = (const float*)d_in[4];
  const float* wv     = (const float*)d_in[5];
  const float* wo     = (const float*)d_in[6];
  const float* wg     = (const float*)d_in[7];
  const float* wl     = (const float*)d_in[8];
  const float* wout   = (const float*)d_in[9];
  const int*   pos    = (const int*)d_in[10];

  char* wsb = (char*)d_ws;
  short* W    = (short*)wsb;
  short* BIG  = (short*)(wsb + (size_t)33554432);
  short* ACT  = (short*)(wsb + (size_t)33554432 + 134217728);

  short* QKV  = BIG;
  short* VT   = BIG + (size_t)NTOK * QKVN;
  short* Hb   = BIG;
  short* Y1   = ACT;
  short* ATTN = ACT;
  short* Y2   = ACT;
  float* X2   = (float*)d_out;

  const dim3 blk(256);
  const dim3 gblk(512);

  k_transpose_f32_bf16<<<dim3(64, 64), blk, 0, stream>>>(wq, W,                   2048, 2048);
  k_transpose_f32_bf16<<<dim3(64, 64), blk, 0, stream>>>(wk, W + 2048 * 2048,     2048, 2048);
  k_transpose_f32_bf16<<<dim3(64, 64), blk, 0, stream>>>(wv, W + 2 * 2048 * 2048, 2048, 2048);

  k_rms_rope<<<NTOK, blk, 0, stream>>>(x, g_attn, pos, Y1);
  k_gemm<0><<<dim3(QKVN / 256, NTOK / 256), gblk, 0, stream>>>(Y1, W, QKV, nullptr, NTOK, QKVN, E_);
  k_transpose_v<<<dim3(S_ / 32, DH_ / 32, B_ * H_), blk, 0, stream>>>(QKV, VT);
  k_flash<<<dim3(S_ / 128, B_ * H_), blk, 0, stream>>>(QKV, VT, ATTN);

  k_transpose_f32_bf16<<<dim3(64, 64), blk, 0, stream>>>(wo, W, 2048, 2048);
  k_gemm<1><<<dim3(E_ / 256, NTOK / 256), gblk, 0, stream>>>(ATTN, W, X2, x, NTOK, E_, E_);

  k_rms<<<NTOK, blk, 0, stream>>>(X2, g_ffn, Y2);

  k_transpose_f32_bf16<<<dim3(256, 64), blk, 0, stream>>>(wg, W, 2048, 8192);
  k_gemm<2><<<dim3(F_ / 256, NTOK / 256), gblk, 0, stream>>>(Y2, W, Hb, nullptr, NTOK, F_, E_);
  k_transpose_f32_bf16<<<dim3(256, 64), blk, 0, stream>>>(wl, W, 2048, 8192);
  k_gemm<3><<<dim3(F_ / 256, NTOK / 256), gblk, 0, stream>>>(Y2, W, Hb, nullptr, NTOK, F_, E_);
  k_transpose_f32_bf16<<<dim3(64, 256), blk, 0, stream>>>(wout, W, 8192, 2048);
  k_gemm<1><<<dim3(E_ / 256, NTOK / 256), gblk, 0, stream>>>(Hb, W, d_out, X2, NTOK, E_, F_);
}

// Round 4
// 1961.379 us; speedup vs baseline: 1.0770x; 1.0361x over previous
//
#include <hip/hip_runtime.h>
#include <cstdint>
#include <cstddef>

#define B_ 4
#define S_ 2048
#define E_ 2048
#define H_ 16
#define DH_ 128
#define F_ 8192
#define NTOK (B_*S_)
#define QKVN (3*E_)

typedef __attribute__((ext_vector_type(4))) float f32x4;
typedef __attribute__((ext_vector_type(8))) __bf16 bf16x8;
typedef __attribute__((ext_vector_type(8))) short s16x8;
typedef __attribute__((ext_vector_type(4))) short s16x4;

using gas_ptr = const __attribute__((address_space(1))) void*;
using las_ptr = __attribute__((address_space(3))) void*;

__device__ __forceinline__ short f2bf(float f) {
  union { float f; uint32_t u; } v{f};
  uint32_t r = v.u + 0x7FFFu + ((v.u >> 16) & 1u);   // round-to-nearest-even
  return (short)(r >> 16);
}
__device__ __forceinline__ float bf2f(short s) {
  union { uint32_t u; float f; } v;
  v.u = ((uint32_t)(uint16_t)s) << 16;
  return v.f;
}

// ---------------- RMSNorm + RoPE -> bf16 ----------------
__global__ __launch_bounds__(256) void k_rms_rope(const float* __restrict__ x,
                                                  const float* __restrict__ gamma,
                                                  const int* __restrict__ pos,
                                                  short* __restrict__ y) {
  const int row = blockIdx.x;
  const int s = row & (S_ - 1);
  const int t = threadIdx.x;
  const int head = t >> 4;
  const int j0 = (t & 15) << 2;
  const float* xr = x + (size_t)row * E_;
  const int c1 = head * DH_ + j0;
  const int c2 = c1 + 64;
  f32x4 x1 = *(const f32x4*)(xr + c1);
  f32x4 x2 = *(const f32x4*)(xr + c2);
  float ss = x1[0]*x1[0]+x1[1]*x1[1]+x1[2]*x1[2]+x1[3]*x1[3]
           + x2[0]*x2[0]+x2[1]*x2[1]+x2[2]*x2[2]+x2[3]*x2[3];
  #pragma unroll
  for (int off = 32; off >= 1; off >>= 1) ss += __shfl_xor(ss, off, 64);
  __shared__ float red[4];
  __shared__ float rsh;
  if ((t & 63) == 0) red[t >> 6] = ss;
  __syncthreads();
  if (t == 0) rsh = rsqrtf((red[0]+red[1]+red[2]+red[3]) * (1.0f / E_) + 1e-5f);
  __syncthreads();
  const float r = rsh;
  f32x4 g1 = *(const f32x4*)(gamma + c1);
  f32x4 g2 = *(const f32x4*)(gamma + c2);
  const float p = (float)pos[s];
  s16x4 o1, o2;
  #pragma unroll
  for (int jj = 0; jj < 4; ++jj) {
    float fi = exp2f((float)(j0 + jj) * (-13.287712379549449f / 64.0f));
    float ang = p * fi;
    float sn, cs;
    sincosf(ang, &sn, &cs);
    float a = x1[jj] * r * g1[jj];
    float b = x2[jj] * r * g2[jj];
    o1[jj] = f2bf(a * cs - b * sn);
    o2[jj] = f2bf(b * cs + a * sn);
  }
  *(s16x4*)(y + (size_t)row * E_ + c1) = o1;
  *(s16x4*)(y + (size_t)row * E_ + c2) = o2;
}

// ---------------- RMSNorm (no rope), fp32 in -> bf16 ----------------
__global__ __launch_bounds__(256) void k_rms(const float* __restrict__ x,
                                             const float* __restrict__ gamma,
                                             short* __restrict__ y) {
  const int row = blockIdx.x;
  const int t = threadIdx.x;
  const int c = t << 3;
  const float* xr = x + (size_t)row * E_;
  f32x4 a = *(const f32x4*)(xr + c);
  f32x4 b = *(const f32x4*)(xr + c + 4);
  float ss = a[0]*a[0]+a[1]*a[1]+a[2]*a[2]+a[3]*a[3]
           + b[0]*b[0]+b[1]*b[1]+b[2]*b[2]+b[3]*b[3];
  #pragma unroll
  for (int off = 32; off >= 1; off >>= 1) ss += __shfl_xor(ss, off, 64);
  __shared__ float red[4];
  __shared__ float rsh;
  if ((t & 63) == 0) red[t >> 6] = ss;
  __syncthreads();
  if (t == 0) rsh = rsqrtf((red[0]+red[1]+red[2]+red[3]) * (1.0f / E_) + 1e-5f);
  __syncthreads();
  const float r = rsh;
  f32x4 ga = *(const f32x4*)(gamma + c);
  f32x4 gb = *(const f32x4*)(gamma + c + 4);
  s16x8 o;
  #pragma unroll
  for (int jj = 0; jj < 4; ++jj) {
    o[jj]   = f2bf(a[jj] * r * ga[jj]);
    o[4+jj] = f2bf(b[jj] * r * gb[jj]);
  }
  *(s16x8*)(y + (size_t)row * E_ + c) = o;
}

// ---------------- fp32 (R,C) -> bf16 (C,R) transpose ----------------
__global__ __launch_bounds__(256) void k_transpose_f32_bf16(const float* __restrict__ src,
                                                            short* __restrict__ dst,
                                                            int R, int C) {
  __shared__ float tile[32][33];
  const int c0 = blockIdx.x << 5, r0 = blockIdx.y << 5;
  const int tx = threadIdx.x & 31, ty = threadIdx.x >> 5;
  #pragma unroll
  for (int j = 0; j < 32; j += 8)
    tile[ty + j][tx] = src[(size_t)(r0 + ty + j) * C + c0 + tx];
  __syncthreads();
  #pragma unroll
  for (int j = 0; j < 32; j += 8)
    dst[(size_t)(c0 + ty + j) * R + r0 + tx] = f2bf(tile[tx][ty + j]);
}

// ---------------- V section of QKV -> per-(b,h) V^T (bf16) ----------------
__global__ __launch_bounds__(256) void k_transpose_v(const short* __restrict__ qkv,
                                                     short* __restrict__ vt) {
  __shared__ short tile[32][33];
  const int bh = blockIdx.z;
  const short* src = qkv + (size_t)(bh >> 4) * S_ * QKVN + 2 * E_ + (bh & 15) * DH_;
  short* dst = vt + (size_t)bh * DH_ * S_;
  const int s0 = blockIdx.x << 5, d0 = blockIdx.y << 5;
  const int tx = threadIdx.x & 31, ty = threadIdx.x >> 5;
  #pragma unroll
  for (int j = 0; j < 32; j += 8)
    tile[ty + j][tx] = src[(size_t)(s0 + ty + j) * QKVN + d0 + tx];
  __syncthreads();
  #pragma unroll
  for (int j = 0; j < 32; j += 8)
    dst[(size_t)(d0 + ty + j) * S_ + s0 + tx] = tile[tx][ty + j];
}

// ---------------- 256x256-tile 8-phase bf16 GEMM (counted-vmcnt schedule) ----------
// C[M,N] = A[M,K] * Bt[N,K]^T.  512 threads = 8 waves (2M x 4N); per-wave output
// 128x64 = acc[8][4].  BK=64; slot = [128 rows][64 cols] bf16 = 16 KiB (128 B rows).
// ROUND-3 POST-MORTEM: 1-bit swizzle spread 16 rows over only 2 of 8 column slots
// -> every ds_read_b128 put 4 lanes on the same 4 banks (banks 16-31 idle),
// SQ_LDS_BANK_CONFLICT 2.5e7, MfmaUtil 27%.  Fix = G4's 3-bit full-spread XOR for
// 128B rows:  byte ^= ((row&7)<<4),  i.e. 16B-chunk' = chunk ^ (row&7).
// Per-instruction bank proof: any aligned 8-lane beat has lh fixed, ll&7 = 0..7
// -> swizzled chunks (kc*4+lh)^(ll&7) are 8 DISTINCT 16B slots = all 32 banks,
// zero conflict; 16-lane beats give 2-way (free, m136).
// Stage keeps LINEAR LDS dest (rule 21); the SOURCE is inverse-swizzled: thread
// tid (LDS row tid>>3, chunk tid&7) fetches global chunk (tid&7)^((tid>>3)&7);
// rows r and r+64 share r&7 so both loads of a stage use the same formula.
// Involution trace: global chunk c_g of row r lands at LDS chunk c_g^(r&7);
// reader asks chunk (kc*4+lh)^(ll&7) with row&7 = ll&7 -> gets c_g = kc*4+lh. OK
// Rings: A = 5 slots (80 KiB), B = 4 slots (64 KiB); slot = (2t+half) mod ring.
// Stage order per tile t: p0 A-hi(t+1), p1 B-lo(t+1), p2 B-hi(t+1), p3 A-lo(t+2);
// every eviction targets a slot whose last ds_read completed >= 4 barriers before
// the stage issues (race-free by barrier order).  Tail stages clamp tile to
// NKT-1 (byte-identical re-issue = benign).  Tile-boundary wait = vmcnt(2),
// never 0 (T3+T4).  T5 setprio(1) around each 16-MFMA cluster.
// EPI: 0 = bf16 store, 1 = fp32 store + fp32 residual(aux), 2 = exact-GELU -> bf16,
//      3 = multiply by existing bf16 in C -> bf16
template<int EPI>
__global__ __launch_bounds__(512, 2) void k_gemm(const short* __restrict__ A,
                                                 const short* __restrict__ Bt,
                                                 void* Cv, const void* aux,
                                                 int M, int N, int K) {
  __shared__ __align__(16) short As[5 * 128 * 64];
  __shared__ __align__(16) short Bs[4 * 128 * 64];
  const int tiles_n = gridDim.x;
  const int nwg = tiles_n * (int)gridDim.y;
  int bid = (int)blockIdx.y * tiles_n + (int)blockIdx.x;
  if ((nwg & 7) == 0) bid = (bid & 7) * (nwg >> 3) + (bid >> 3);   // XCD swizzle
  const int m_tile = bid / tiles_n, n_tile = bid - m_tile * tiles_n;
  const int m0 = m_tile << 8, n0 = n_tile << 8;

  const int tid = threadIdx.x;
  const int wave = tid >> 6, lane = tid & 63;
  const int ll = lane & 15, lh = lane >> 4;
  const int wm = wave >> 2, wn = wave & 3;

  // ---- staging geometry (inverse-swizzled source, linear LDS dest) ----
  const int sr = tid >> 3;                               // row 0..63 in block
  const int chk = (tid & 7) ^ (sr & 7);                  // pre-swizzled 16B chunk
  const short* Ag0 = A  + (size_t)(m0 + sr) * K + chk * 8;
  const short* Bg0 = Bt + (size_t)(n0 + sr) * K + chk * 8;
  const int wuB = wave << 9;                             // wave*1024 B in shorts

  const int NKT = K >> 6;

  auto STAGE_A = [&](int t2, int half) {
    if (t2 > NKT - 1) t2 = NKT - 1;                      // tail clamp (idempotent)
    const int sl = ((2 * t2 + half) % 5) << 13;          // slot * 8192 shorts
    const short* src = Ag0 + (size_t)(half * 128) * K + t2 * 64;
    __builtin_amdgcn_global_load_lds((gas_ptr)src,
                                     (las_ptr)(As + sl + wuB), 16, 0, 0);
    __builtin_amdgcn_global_load_lds((gas_ptr)(src + (size_t)64 * K),
                                     (las_ptr)(As + sl + 4096 + wuB), 16, 0, 0);
  };
  auto STAGE_B = [&](int t2, int half) {
    if (t2 > NKT - 1) t2 = NKT - 1;
    const int sl = ((2 * t2 + half) & 3) << 13;
    const short* src = Bg0 + (size_t)(half * 128) * K + t2 * 64;
    __builtin_amdgcn_global_load_lds((gas_ptr)src,
                                     (las_ptr)(Bs + sl + wuB), 16, 0, 0);
    __builtin_amdgcn_global_load_lds((gas_ptr)(src + (size_t)64 * K),
                                     (las_ptr)(Bs + sl + 4096 + wuB), 16, 0, 0);
  };

  const f32x4 fz = {0.f, 0.f, 0.f, 0.f};
  f32x4 acc[8][4];
  #pragma unroll
  for (int i = 0; i < 8; ++i)
    #pragma unroll
    for (int j = 0; j < 4; ++j) acc[i][j] = fz;

  // ---- reader offsets (shorts, within slot) ----
  // row r in slot: A: mf*16+ll (wave wm reads slot 2t+wm); B: (wn&1)*64+nf*16+ll
  // chunk = (kc*4 + lh) ^ (row&7) = (kc*4 + lh) ^ (ll&7);  col = chunk*8 shorts
  const int c0s = ((lh ^ (ll & 7)) << 3);        // kc = 0
  const int c1s = c0s ^ 32;                      // kc = 1  ((4+lh)^(ll&7))<<3
  const int rAb = (ll << 6);                     // + mf*1024
  const int rBb = ((wn & 1) << 12) + (ll << 6);  // + nf*1024

  // ---- prologue: tile0 all 4 halves + A-lo(1); wait tile0 (vmcnt(2)) ----
  STAGE_A(0, 0); STAGE_A(0, 1); STAGE_B(0, 0); STAGE_B(0, 1); STAGE_A(1, 0);
  asm volatile("s_waitcnt vmcnt(2)" ::: "memory");
  __builtin_amdgcn_s_barrier();

  for (int kt = 0; kt < NKT; ++kt) {
    const int slA = ((2 * kt + wm) % 5) << 13;
    const int slB = ((2 * kt + (wn >> 1)) & 3) << 13;
    bf16x8 bA[4], bB[4];

    // ---- phase 0: kc0, mf0-3 ----
    #pragma unroll
    for (int nf = 0; nf < 4; ++nf) bB[nf] = *(const bf16x8*)&Bs[slB + rBb + nf * 1024 + c0s];
    #pragma unroll
    for (int mf = 0; mf < 4; ++mf) bA[mf] = *(const bf16x8*)&As[slA + rAb + mf * 1024 + c0s];
    STAGE_A(kt + 1, 1);
    __builtin_amdgcn_s_barrier();
    asm volatile("s_waitcnt lgkmcnt(0)" ::: "memory");
    __builtin_amdgcn_s_setprio(1);
    #pragma unroll
    for (int mf = 0; mf < 4; ++mf)
      #pragma unroll
      for (int nf = 0; nf < 4; ++nf)
        acc[mf][nf] = __builtin_amdgcn_mfma_f32_16x16x32_bf16(bA[mf], bB[nf], acc[mf][nf], 0, 0, 0);
    __builtin_amdgcn_s_setprio(0);
    __builtin_amdgcn_s_barrier();

    // ---- phase 1: kc0, mf4-7 ----
    #pragma unroll
    for (int mf = 0; mf < 4; ++mf) bA[mf] = *(const bf16x8*)&As[slA + rAb + (mf + 4) * 1024 + c0s];
    STAGE_B(kt + 1, 0);
    __builtin_amdgcn_s_barrier();
    asm volatile("s_waitcnt lgkmcnt(0)" ::: "memory");
    __builtin_amdgcn_s_setprio(1);
    #pragma unroll
    for (int mf = 0; mf < 4; ++mf)
      #pragma unroll
      for (int nf = 0; nf < 4; ++nf)
        acc[4 + mf][nf] = __builtin_amdgcn_mfma_f32_16x16x32_bf16(bA[mf], bB[nf], acc[4 + mf][nf], 0, 0, 0);
    __builtin_amdgcn_s_setprio(0);
    __builtin_amdgcn_s_barrier();

    // ---- phase 2: kc1, mf0-3 ----
    #pragma unroll
    for (int nf = 0; nf < 4; ++nf) bB[nf] = *(const bf16x8*)&Bs[slB + rBb + nf * 1024 + c1s];
    #pragma unroll
    for (int mf = 0; mf < 4; ++mf) bA[mf] = *(const bf16x8*)&As[slA + rAb + mf * 1024 + c1s];
    STAGE_B(kt + 1, 1);
    __builtin_amdgcn_s_barrier();
    asm volatile("s_waitcnt lgkmcnt(0)" ::: "memory");
    __builtin_amdgcn_s_setprio(1);
    #pragma unroll
    for (int mf = 0; mf < 4; ++mf)
      #pragma unroll
      for (int nf = 0; nf < 4; ++nf)
        acc[mf][nf] = __builtin_amdgcn_mfma_f32_16x16x32_bf16(bA[mf], bB[nf], acc[mf][nf], 0, 0, 0);
    __builtin_amdgcn_s_setprio(0);
    __builtin_amdgcn_s_barrier();

    // ---- phase 3: kc1, mf4-7 (+ the one counted wait per K-tile) ----
    #pragma unroll
    for (int mf = 0; mf < 4; ++mf) bA[mf] = *(const bf16x8*)&As[slA + rAb + (mf + 4) * 1024 + c1s];
    STAGE_A(kt + 2, 0);
    __builtin_amdgcn_s_barrier();
    asm volatile("s_waitcnt lgkmcnt(0)" ::: "memory");
    __builtin_amdgcn_s_setprio(1);
    #pragma unroll
    for (int mf = 0; mf < 4; ++mf)
      #pragma unroll
      for (int nf = 0; nf < 4; ++nf)
        acc[4 + mf][nf] = __builtin_amdgcn_mfma_f32_16x16x32_bf16(bA[mf], bB[nf], acc[4 + mf][nf], 0, 0, 0);
    __builtin_amdgcn_s_setprio(0);
    asm volatile("s_waitcnt vmcnt(2)" ::: "memory");   // tile kt+1 fully landed
    __builtin_amdgcn_s_barrier();
  }

  // epilogue; verified C/D layout: col = lane&15, row = (lane>>4)*4 + reg
  #pragma unroll
  for (int mf = 0; mf < 8; ++mf) {
    const int row = m0 + (wm << 7) + (mf << 4) + (lh << 2);
    #pragma unroll
    for (int nf = 0; nf < 4; ++nf) {
      const int col = n0 + (wn << 6) + (nf << 4) + ll;
      #pragma unroll
      for (int rg = 0; rg < 4; ++rg) {
        const float c = acc[mf][nf][rg];
        const size_t idx = (size_t)(row + rg) * N + col;
        if constexpr (EPI == 0) {
          ((short*)Cv)[idx] = f2bf(c);
        } else if constexpr (EPI == 1) {
          ((float*)Cv)[idx] = c + ((const float*)aux)[idx];
        } else if constexpr (EPI == 2) {
          float gl = 0.5f * c * (1.0f + erff(c * 0.70710678118654752f));
          ((short*)Cv)[idx] = f2bf(gl);
        } else {
          float gl = bf2f(((short*)Cv)[idx]);
          ((short*)Cv)[idx] = f2bf(c * gl);
        }
      }
    }
  }
}

// ---------------- flash attention ----------------
#define CEXP 0.12752682475470602f   // log2(e)/sqrt(128)
__global__ __launch_bounds__(256, 2) void k_flash(const short* __restrict__ qkv,
                                                  const short* __restrict__ vt,
                                                  short* __restrict__ attn) {
  __shared__ short Kt[64][136];
  __shared__ short VtT[128][72];
  __shared__ short Pt[4][32][72];
  const int qt = blockIdx.x, bh = blockIdx.y;
  const int b = bh >> 4, h = bh & 15;
  const int q0 = qt << 7;
  const int tid = threadIdx.x, wave = tid >> 6, lane = tid & 63;
  const int ll = lane & 15, lh = lane >> 4;
  const short* qbase = qkv + (size_t)b * S_ * QKVN + h * DH_;
  const short* kbase = qbase + E_;
  const short* vbase = vt + (size_t)bh * DH_ * S_;

  bf16x8 qf[2][4];
  #pragma unroll
  for (int mt = 0; mt < 2; ++mt) {
    const short* qr = qbase + (size_t)(q0 + wave * 32 + mt * 16 + ll) * QKVN;
    #pragma unroll
    for (int kc = 0; kc < 4; ++kc) qf[mt][kc] = *(const bf16x8*)(qr + kc * 32 + lh * 8);
  }

  const f32x4 fzero = {0.f, 0.f, 0.f, 0.f};
  float m_i[2][4], l_i[2][4];
  f32x4 oacc[2][8];
  #pragma unroll
  for (int mt = 0; mt < 2; ++mt) {
    #pragma unroll
    for (int rg = 0; rg < 4; ++rg) { m_i[mt][rg] = -1e30f; l_i[mt][rg] = 0.f; }
    #pragma unroll
    for (int n8 = 0; n8 < 8; ++n8) oacc[mt][n8] = fzero;
  }

  const int nkt = (q0 + 128) >> 6;
  for (int kt = 0; kt < nkt; ++kt) {
    const int k0 = kt << 6;
    __syncthreads();
    #pragma unroll
    for (int p = 0; p < 4; ++p) {
      int idx = p * 256 + tid;
      int r = idx >> 4, c0 = (idx & 15) << 3;
      *(s16x8*)&Kt[r][c0] = *(const s16x8*)(kbase + (size_t)(k0 + r) * QKVN + c0);
      int dh = idx >> 3, kk = (idx & 7) << 3;
      *(s16x8*)&VtT[dh][kk] = *(const s16x8*)(vbase + (size_t)dh * S_ + k0 + kk);
    }
    __syncthreads();

    f32x4 sc[2][4];
    #pragma unroll
    for (int mt = 0; mt < 2; ++mt)
      #pragma unroll
      for (int nt = 0; nt < 4; ++nt) sc[mt][nt] = fzero;
    #pragma unroll
    for (int kc = 0; kc < 4; ++kc) {
      bf16x8 kb[4];
      #pragma unroll
      for (int nt = 0; nt < 4; ++nt)
        kb[nt] = *(const bf16x8*)&Kt[nt * 16 + ll][kc * 32 + lh * 8];
      #pragma unroll
      for (int mt = 0; mt < 2; ++mt)
        #pragma unroll
        for (int nt = 0; nt < 4; ++nt)
          sc[mt][nt] = __builtin_amdgcn_mfma_f32_16x16x32_bf16(qf[mt][kc], kb[nt], sc[mt][nt], 0, 0, 0);
    }

    if (k0 + 63 > q0) {
      #pragma unroll
      for (int mt = 0; mt < 2; ++mt)
        #pragma unroll
        for (int nt = 0; nt < 4; ++nt)
          #pragma unroll
          for (int rg = 0; rg < 4; ++rg) {
            int kidx = k0 + nt * 16 + ll;
            int qidx = q0 + wave * 32 + mt * 16 + lh * 4 + rg;
            if (kidx > qidx) sc[mt][nt][rg] = -1e30f;
          }
    }

    #pragma unroll
    for (int mt = 0; mt < 2; ++mt)
      #pragma unroll
      for (int rg = 0; rg < 4; ++rg) {
        float mx = fmaxf(fmaxf(sc[mt][0][rg], sc[mt][1][rg]),
                         fmaxf(sc[mt][2][rg], sc[mt][3][rg]));
        #pragma unroll
        for (int off = 1; off < 16; off <<= 1) mx = fmaxf(mx, __shfl_xor(mx, off, 64));
        float mn = fmaxf(m_i[mt][rg], mx);
        float al = exp2f((m_i[mt][rg] - mn) * CEXP);
        m_i[mt][rg] = mn;
        float rsum = 0.f;
        #pragma unroll
        for (int nt = 0; nt < 4; ++nt) {
          float pv = exp2f((sc[mt][nt][rg] - mn) * CEXP);
          sc[mt][nt][rg] = pv;
          rsum += pv;
        }
        #pragma unroll
        for (int off = 1; off < 16; off <<= 1) rsum += __shfl_xor(rsum, off, 64);
        l_i[mt][rg] = l_i[mt][rg] * al + rsum;
        #pragma unroll
        for (int n8 = 0; n8 < 8; ++n8) oacc[mt][n8][rg] *= al;
      }

    #pragma unroll
    for (int mt = 0; mt < 2; ++mt)
      #pragma unroll
      for (int nt = 0; nt < 4; ++nt)
        #pragma unroll
        for (int rg = 0; rg < 4; ++rg)
          Pt[wave][mt * 16 + lh * 4 + rg][nt * 16 + ll] = f2bf(sc[mt][nt][rg]);

    #pragma unroll
    for (int kc2 = 0; kc2 < 2; ++kc2) {
      bf16x8 pa[2];
      #pragma unroll
      for (int mt = 0; mt < 2; ++mt)
        pa[mt] = *(const bf16x8*)&Pt[wave][mt * 16 + ll][kc2 * 32 + lh * 8];
      #pragma unroll
      for (int n8 = 0; n8 < 8; ++n8) {
        bf16x8 vb = *(const bf16x8*)&VtT[n8 * 16 + ll][kc2 * 32 + lh * 8];
        #pragma unroll
        for (int mt = 0; mt < 2; ++mt)
          oacc[mt][n8] = __builtin_amdgcn_mfma_f32_16x16x32_bf16(pa[mt], vb, oacc[mt][n8], 0, 0, 0);
      }
    }
  }

  short* ab = attn + (size_t)(b * S_) * E_ + h * DH_;
  #pragma unroll
  for (int mt = 0; mt < 2; ++mt) {
    const int row = q0 + wave * 32 + mt * 16 + lh * 4;
    #pragma unroll
    for (int n8 = 0; n8 < 8; ++n8) {
      const int col = n8 * 16 + ll;
      #pragma unroll
      for (int rg = 0; rg < 4; ++rg)
        ab[(size_t)(row + rg) * E_ + col] = f2bf(oacc[mt][n8][rg] / l_i[mt][rg]);
    }
  }
}

// ---------------- launch ----------------
// Workspace plan (192 MiB; single stream => lifetime-disjoint aliasing is safe):
//   W slot   [ 33,554,432 B]  each weight transposed here right before its GEMM
//   big slot [134,217,728 B]  phase 1: QKV | VT; phase 2: Hb
//   act slot [ 33,554,432 B]  Y1 -> ATTN -> Y2
//   X2 (fp32 residual stream) lives in d_out, overwritten by the final GEMM.
extern "C" void kernel_launch(void* const* d_in, const int* in_sizes, int n_in,
                              void* d_out, int out_size, void* d_ws, size_t ws_size,
                              hipStream_t stream) {
  (void)in_sizes; (void)n_in; (void)out_size; (void)ws_size;
  const float* x      = (const float*)d_in[0];
  const float* g_attn = (const float*)d_in[1];
  const float* g_ffn  = (const float*)d_in[2];
  const float* wq     = (const float*)d_in[3];
  const float* wk     = (const float*)d_in[4];
  const float* wv     = (const float*)d_in[5];
  const float* wo     = (const float*)d_in[6];
  const float* wg     = (const float*)d_in[7];
  const float* wl     = (const float*)d_in[8];
  const float* wout   = (const float*)d_in[9];
  const int*   pos    = (const int*)d_in[10];

  char* wsb = (char*)d_ws;
  short* W    = (short*)wsb;
  short* BIG  = (short*)(wsb + (size_t)33554432);
  short* ACT  = (short*)(wsb + (size_t)33554432 + 134217728);

  short* QKV  = BIG;
  short* VT   = BIG + (size_t)NTOK * QKVN;
  short* Hb   = BIG;
  short* Y1   = ACT;
  short* ATTN = ACT;
  short* Y2   = ACT;
  float* X2   = (float*)d_out;

  const dim3 blk(256);
  const dim3 gblk(512);

  k_transpose_f32_bf16<<<dim3(64, 64), blk, 0, stream>>>(wq, W,                   2048, 2048);
  k_transpose_f32_bf16<<<dim3(64, 64), blk, 0, stream>>>(wk, W + 2048 * 2048,     2048, 2048);
  k_transpose_f32_bf16<<<dim3(64, 64), blk, 0, stream>>>(wv, W + 2 * 2048 * 2048, 2048, 2048);

  k_rms_rope<<<NTOK, blk, 0, stream>>>(x, g_attn, pos, Y1);
  k_gemm<0><<<dim3(QKVN / 256, NTOK / 256), gblk, 0, stream>>>(Y1, W, QKV, nullptr, NTOK, QKVN, E_);
  k_transpose_v<<<dim3(S_ / 32, DH_ / 32, B_ * H_), blk, 0, stream>>>(QKV, VT);
  k_flash<<<dim3(S_ / 128, B_ * H_), blk, 0, stream>>>(QKV, VT, ATTN);

  k_transpose_f32_bf16<<<dim3(64, 64), blk, 0, stream>>>(wo, W, 2048, 2048);
  k_gemm<1><<<dim3(E_ / 256, NTOK / 256), gblk, 0, stream>>>(ATTN, W, X2, x, NTOK, E_, E_);

  k_rms<<<NTOK, blk, 0, stream>>>(X2, g_ffn, Y2);

  k_transpose_f32_bf16<<<dim3(256, 64), blk, 0, stream>>>(wg, W, 2048, 8192);
  k_gemm<2><<<dim3(F_ / 256, NTOK / 256), gblk, 0, stream>>>(Y2, W, Hb, nullptr, NTOK, F_, E_);
  k_transpose_f32_bf16<<<dim3(256, 64), blk, 0, stream>>>(wl, W, 2048, 8192);
  k_gemm<3><<<dim3(F_ / 256, NTOK / 256), gblk, 0, stream>>>(Y2, W, Hb, nullptr, NTOK, F_, E_);
  k_transpose_f32_bf16<<<dim3(64, 256), blk, 0, stream>>>(wout, W, 8192, 2048);
  k_gemm<1><<<dim3(E_ / 256, NTOK / 256), gblk, 0, stream>>>(Hb, W, d_out, X2, NTOK, E_, F_);
}